// Round 1
// baseline (80.196 us; speedup 1.0000x reference)
//
#include <hip/hip_runtime.h>
#include <math.h>

#define NM 16   // modes
#define NL 6    // layers
#define NW 15   // beamsplitters per layer
#define S2H 2.0f  // sqrt(2*hbar)

// ws layout (floats): W[32][16] row-major at [0,512), bias[32] at [512,544)

__global__ __launch_bounds__(640) void cv_precompute(
    const float* __restrict__ disp,   // [2][NL][NM][2]
    const float* __restrict__ sq,     // [2][NL][NM][2]
    const float* __restrict__ bs,     // [2][NL][NW][2]
    float* __restrict__ ws)
{
    __shared__ float dxc[2][NL][NM], dpc[2][NL][NM];
    __shared__ float s00[2][NL][NM], s01[2][NL][NM], s11[2][NL][NM];
    __shared__ float bct[2][NL][NW], bcs[2][NL][NW], bss[2][NL][NW];

    int t = threadIdx.x;
    // Phase 1: parallel transcendental precompute into LDS
    if (t < 192) {
        int c = t / 96, rem = t % 96, l = rem / NM, n = rem % NM;
        float a  = disp[((c*NL + l)*NM + n)*2 + 0];
        float ph = disp[((c*NL + l)*NM + n)*2 + 1];
        dxc[c][l][n] = S2H * a * cosf(ph);
        dpc[c][l][n] = S2H * a * sinf(ph);
    } else if (t < 384) {
        int i = t - 192;
        int c = i / 96, rem = i % 96, l = rem / NM, n = rem % NM;
        float r  = fabsf(sq[((c*NL + l)*NM + n)*2 + 0]);
        float ph = sq[((c*NL + l)*NM + n)*2 + 1];
        float ch = coshf(r), sh = sinhf(r);
        float cp = cosf(ph), sp = sinf(ph);
        s00[c][l][n] = ch - cp*sh;
        s01[c][l][n] = -sp*sh;
        s11[c][l][n] = ch + cp*sh;
    } else if (t < 564) {
        int i = t - 384;
        int c = i / 90, rem = i % 90, l = rem / NW, w = rem % NW;
        float z  = bs[((c*NL + l)*NW + w)*2 + 0];
        float ph = bs[((c*NL + l)*NW + w)*2 + 1];
        float th = 1.0f / (1.0f + expf(-z));
        float ct = cosf(th), st = sinf(th);
        bct[c][l][w] = ct;
        bcs[c][l][w] = cosf(ph) * st;
        bss[c][l][w] = sinf(ph) * st;
    }
    __syncthreads();

    // Phase 2: 34 threads propagate basis vectors (pure FMA chain).
    // col < 16: linear part column (no displacement). col == 16: bias (zero
    // input, WITH displacement). Affine map F(x)=Mx+c decomposes exactly so.
    if (t >= 34) return;
    int c = t / 17;
    int col = t % 17;
    bool isBias = (col == NM);

    float mx[NM], mp[NM];
    #pragma unroll
    for (int n = 0; n < NM; ++n) { mx[n] = 0.f; mp[n] = 0.f; }
    if (!isBias) mx[col] = S2H;   // mx = S2H * x

    for (int l = 0; l < NL; ++l) {
        if (isBias) {
            #pragma unroll
            for (int n = 0; n < NM; ++n) { mx[n] += dxc[c][l][n]; mp[n] += dpc[c][l][n]; }
        }
        #pragma unroll
        for (int n = 0; n < NM; ++n) {
            float a = s00[c][l][n], b = s01[c][l][n], d = s11[c][l][n];
            float nx  = a*mx[n] + b*mp[n];
            float npp = b*mx[n] + d*mp[n];
            mx[n] = nx; mp[n] = npp;
        }
        #pragma unroll
        for (int w = 0; w < NW; ++w) {
            float ct = bct[c][l][w], cst = bcs[c][l][w], sst = bss[c][l][w];
            float x1 = mx[w], x2 = mx[w+1], p1 = mp[w], p2 = mp[w+1];
            mx[w]   = ct*x1  - cst*x2 - sst*p2;
            mx[w+1] = cst*x1 + ct*x2  - sst*p1;
            mp[w]   = sst*x2 + ct*p1  - cst*p2;
            mp[w+1] = sst*x1 + cst*p1 + ct*p2;
        }
    }

    if (c == 0) {
        if (!isBias) {
            #pragma unroll
            for (int n = 0; n < NM; ++n) ws[n*16 + col] = mx[n];
        } else {
            #pragma unroll
            for (int n = 0; n < NM; ++n) ws[512 + n] = mx[n];
        }
    } else {
        if (!isBias) {
            #pragma unroll
            for (int n = 0; n < NM; ++n) ws[(16 + n)*16 + col] = mp[n];
        } else {
            #pragma unroll
            for (int n = 0; n < NM; ++n) ws[512 + 16 + n] = mp[n];
        }
    }
}

// Main kernel: out[b,:] = W @ x[b,:] + bias, 2 samples per thread.
__global__ __launch_bounds__(256) void cv_apply(
    const float* __restrict__ x,
    const float* __restrict__ ws,
    float* __restrict__ out,
    int half)                           // half = B/2
{
    __shared__ float4 sW[128];          // sW[n*4+q] = W[n][4q..4q+3]
    __shared__ float  sB[32];
    if (threadIdx.x < 128) sW[threadIdx.x] = ((const float4*)ws)[threadIdx.x];
    if (threadIdx.x < 32)  sB[threadIdx.x] = ws[512 + threadIdx.x];
    __syncthreads();

    int tid = blockIdx.x * 256 + threadIdx.x;
    if (tid >= half) return;
    size_t s0 = (size_t)tid;
    size_t s1 = (size_t)tid + (size_t)half;

    float xr0[16], xr1[16];
    const float4* xv0 = (const float4*)(x + s0 * 16);
    const float4* xv1 = (const float4*)(x + s1 * 16);
    #pragma unroll
    for (int q = 0; q < 4; ++q) {
        float4 v = xv0[q];
        xr0[q*4+0] = v.x; xr0[q*4+1] = v.y; xr0[q*4+2] = v.z; xr0[q*4+3] = v.w;
    }
    #pragma unroll
    for (int q = 0; q < 4; ++q) {
        float4 v = xv1[q];
        xr1[q*4+0] = v.x; xr1[q*4+1] = v.y; xr1[q*4+2] = v.z; xr1[q*4+3] = v.w;
    }

    float* o0 = out + s0 * 32;
    float* o1 = out + s1 * 32;
    #pragma unroll
    for (int nc = 0; nc < 8; ++nc) {
        float a0[4], a1[4];
        #pragma unroll
        for (int j = 0; j < 4; ++j) {
            int n = nc*4 + j;
            float acc0 = sB[n], acc1 = sB[n];
            #pragma unroll
            for (int q = 0; q < 4; ++q) {
                float4 w = sW[n*4 + q];   // wave-uniform -> LDS broadcast
                acc0 = fmaf(w.x, xr0[q*4+0], acc0);
                acc0 = fmaf(w.y, xr0[q*4+1], acc0);
                acc0 = fmaf(w.z, xr0[q*4+2], acc0);
                acc0 = fmaf(w.w, xr0[q*4+3], acc0);
                acc1 = fmaf(w.x, xr1[q*4+0], acc1);
                acc1 = fmaf(w.y, xr1[q*4+1], acc1);
                acc1 = fmaf(w.z, xr1[q*4+2], acc1);
                acc1 = fmaf(w.w, xr1[q*4+3], acc1);
            }
            a0[j] = acc0; a1[j] = acc1;
        }
        *(float4*)(o0 + nc*4) = make_float4(a0[0], a0[1], a0[2], a0[3]);
        *(float4*)(o1 + nc*4) = make_float4(a1[0], a1[1], a1[2], a1[3]);
    }
}

extern "C" void kernel_launch(void* const* d_in, const int* in_sizes, int n_in,
                              void* d_out, int out_size, void* d_ws, size_t ws_size,
                              hipStream_t stream) {
    const float* x    = (const float*)d_in[0];
    const float* disp = (const float*)d_in[1];
    const float* sq   = (const float*)d_in[2];
    const float* bs   = (const float*)d_in[3];
    float* ws  = (float*)d_ws;
    float* out = (float*)d_out;

    int B = in_sizes[0] / NM;
    int half = B / 2;

    cv_precompute<<<1, 640, 0, stream>>>(disp, sq, bs, ws);
    int blocks = (half + 255) / 256;
    cv_apply<<<blocks, 256, 0, stream>>>(x, ws, out, half);
}

// Round 2
// 58.736 us; speedup vs baseline: 1.3654x; 1.3654x over previous
//
#include <hip/hip_runtime.h>
#include <math.h>

#define NM 16   // modes
#define NL 6    // layers
#define NW 15   // beamsplitters per layer
#define S2H 2.0f  // sqrt(2*hbar)

// ws layout (floats): W[32][16] row-major at [0,512), bias[32] at [512,544)

__global__ __launch_bounds__(640) void cv_precompute(
    const float* __restrict__ disp,   // [2][NL][NM][2]
    const float* __restrict__ sq,     // [2][NL][NM][2]
    const float* __restrict__ bs,     // [2][NL][NW][2]
    float* __restrict__ ws)
{
    __shared__ float dxc[2][NL][NM], dpc[2][NL][NM];
    __shared__ float s00[2][NL][NM], s01[2][NL][NM], s11[2][NL][NM];
    __shared__ float bct[2][NL][NW], bcs[2][NL][NW], bss[2][NL][NW];

    int t = threadIdx.x;
    // Phase 1: parallel transcendental precompute into LDS
    if (t < 192) {
        int c = t / 96, rem = t % 96, l = rem / NM, n = rem % NM;
        float a  = disp[((c*NL + l)*NM + n)*2 + 0];
        float ph = disp[((c*NL + l)*NM + n)*2 + 1];
        dxc[c][l][n] = S2H * a * cosf(ph);
        dpc[c][l][n] = S2H * a * sinf(ph);
    } else if (t < 384) {
        int i = t - 192;
        int c = i / 96, rem = i % 96, l = rem / NM, n = rem % NM;
        float r  = fabsf(sq[((c*NL + l)*NM + n)*2 + 0]);
        float ph = sq[((c*NL + l)*NM + n)*2 + 1];
        float ch = coshf(r), sh = sinhf(r);
        float cp = cosf(ph), sp = sinf(ph);
        s00[c][l][n] = ch - cp*sh;
        s01[c][l][n] = -sp*sh;
        s11[c][l][n] = ch + cp*sh;
    } else if (t < 564) {
        int i = t - 384;
        int c = i / 90, rem = i % 90, l = rem / NW, w = rem % NW;
        float z  = bs[((c*NL + l)*NW + w)*2 + 0];
        float ph = bs[((c*NL + l)*NW + w)*2 + 1];
        float th = 1.0f / (1.0f + expf(-z));
        float ct = cosf(th), st = sinf(th);
        bct[c][l][w] = ct;
        bcs[c][l][w] = cosf(ph) * st;
        bss[c][l][w] = sinf(ph) * st;
    }
    __syncthreads();

    // Phase 2: 34 threads propagate basis vectors (pure FMA chain).
    // col < 16: linear part column (no displacement). col == 16: bias (zero
    // input, WITH displacement). Affine map F(x)=Mx+c decomposes exactly so.
    if (t >= 34) return;
    int c = t / 17;
    int col = t % 17;
    bool isBias = (col == NM);

    float mx[NM], mp[NM];
    #pragma unroll
    for (int n = 0; n < NM; ++n) { mx[n] = 0.f; mp[n] = 0.f; }
    if (!isBias) mx[col] = S2H;   // mx = S2H * x

    for (int l = 0; l < NL; ++l) {
        if (isBias) {
            #pragma unroll
            for (int n = 0; n < NM; ++n) { mx[n] += dxc[c][l][n]; mp[n] += dpc[c][l][n]; }
        }
        #pragma unroll
        for (int n = 0; n < NM; ++n) {
            float a = s00[c][l][n], b = s01[c][l][n], d = s11[c][l][n];
            float nx  = a*mx[n] + b*mp[n];
            float npp = b*mx[n] + d*mp[n];
            mx[n] = nx; mp[n] = npp;
        }
        #pragma unroll
        for (int w = 0; w < NW; ++w) {
            float ct = bct[c][l][w], cst = bcs[c][l][w], sst = bss[c][l][w];
            float x1 = mx[w], x2 = mx[w+1], p1 = mp[w], p2 = mp[w+1];
            mx[w]   = ct*x1  - cst*x2 - sst*p2;
            mx[w+1] = cst*x1 + ct*x2  - sst*p1;
            mp[w]   = sst*x2 + ct*p1  - cst*p2;
            mp[w+1] = sst*x1 + cst*p1 + ct*p2;
        }
    }

    if (c == 0) {
        if (!isBias) {
            #pragma unroll
            for (int n = 0; n < NM; ++n) ws[n*16 + col] = mx[n];
        } else {
            #pragma unroll
            for (int n = 0; n < NM; ++n) ws[512 + n] = mx[n];
        }
    } else {
        if (!isBias) {
            #pragma unroll
            for (int n = 0; n < NM; ++n) ws[(16 + n)*16 + col] = mp[n];
        } else {
            #pragma unroll
            for (int n = 0; n < NM; ++n) ws[512 + 16 + n] = mp[n];
        }
    }
}

// Main kernel: each thread produces one float4 OUTPUT CHUNK k = b*8 + c,
// i.e. out[b][4c..4c+4). Since 256 and gridDim*256 are multiples of 8,
// c = threadIdx.x & 7 is FIXED per thread -> its 4 W rows + bias live in
// registers. Stores are perfectly lane-coalesced (consecutive float4s);
// x loads span a contiguous 512 B window per wave (8 lanes share a sample,
// duplicate addresses merge in the coalescer). No LDS, no barriers.
__global__ __launch_bounds__(256) void cv_apply(
    const float* __restrict__ x,
    const float* __restrict__ ws,
    float* __restrict__ out,
    long long nchunks)                  // B * 8
{
    const int c = threadIdx.x & 7;

    // Preload this lane's 4 W rows (n = 4c+j) and bias into registers.
    float4 w[4][4];
    float  bias[4];
    #pragma unroll
    for (int j = 0; j < 4; ++j) {
        const int n = c * 4 + j;
        #pragma unroll
        for (int q = 0; q < 4; ++q)
            w[j][q] = ((const float4*)ws)[n * 4 + q];
        bias[j] = ws[512 + n];
    }

    const long long G = (long long)gridDim.x * 256;
    for (long long k = (long long)blockIdx.x * 256 + threadIdx.x;
         k < nchunks; k += G) {
        const long long b = k >> 3;                 // sample index
        const float4* xp = (const float4*)(x + b * 16);
        float xr[16];
        #pragma unroll
        for (int q = 0; q < 4; ++q) {
            float4 v = xp[q];
            xr[q*4+0] = v.x; xr[q*4+1] = v.y; xr[q*4+2] = v.z; xr[q*4+3] = v.w;
        }

        float acc[4];
        #pragma unroll
        for (int j = 0; j < 4; ++j) acc[j] = bias[j];
        #pragma unroll
        for (int q = 0; q < 4; ++q) {
            #pragma unroll
            for (int j = 0; j < 4; ++j) {
                acc[j] = fmaf(w[j][q].x, xr[q*4+0], acc[j]);
                acc[j] = fmaf(w[j][q].y, xr[q*4+1], acc[j]);
                acc[j] = fmaf(w[j][q].z, xr[q*4+2], acc[j]);
                acc[j] = fmaf(w[j][q].w, xr[q*4+3], acc[j]);
            }
        }

        *(float4*)(out + (size_t)k * 4) =
            make_float4(acc[0], acc[1], acc[2], acc[3]);
    }
}

extern "C" void kernel_launch(void* const* d_in, const int* in_sizes, int n_in,
                              void* d_out, int out_size, void* d_ws, size_t ws_size,
                              hipStream_t stream) {
    const float* x    = (const float*)d_in[0];
    const float* disp = (const float*)d_in[1];
    const float* sq   = (const float*)d_in[2];
    const float* bs   = (const float*)d_in[3];
    float* ws  = (float*)d_ws;
    float* out = (float*)d_out;

    long long B = in_sizes[0] / NM;
    long long nchunks = B * 8;

    cv_precompute<<<1, 640, 0, stream>>>(disp, sq, bs, ws);

    // ~16 grid-stride iterations/thread; 2048 blocks = 8 blocks/CU.
    long long want = (nchunks + 255) / 256;
    int blocks = (int)(want < 2048 ? want : 2048);
    cv_apply<<<blocks, 256, 0, stream>>>(x, ws, out, nchunks);
}

// Round 3
// 58.183 us; speedup vs baseline: 1.3783x; 1.0095x over previous
//
#include <hip/hip_runtime.h>
#include <math.h>

#define NM 16   // modes
#define NL 6    // layers
#define NW 15   // beamsplitters per layer
#define S2H 2.0f  // sqrt(2*hbar)

typedef float v4f __attribute__((ext_vector_type(4)));

// ws layout (floats): W[32][16] row-major at [0,512), bias[32] at [512,544)

__global__ __launch_bounds__(640) void cv_precompute(
    const float* __restrict__ disp,   // [2][NL][NM][2]
    const float* __restrict__ sq,     // [2][NL][NM][2]
    const float* __restrict__ bs,     // [2][NL][NW][2]
    float* __restrict__ ws)
{
    __shared__ float dxc[2][NL][NM], dpc[2][NL][NM];
    __shared__ float s00[2][NL][NM], s01[2][NL][NM], s11[2][NL][NM];
    __shared__ float bct[2][NL][NW], bcs[2][NL][NW], bss[2][NL][NW];

    int t = threadIdx.x;
    // Phase 1: parallel transcendental precompute into LDS
    if (t < 192) {
        int c = t / 96, rem = t % 96, l = rem / NM, n = rem % NM;
        float a  = disp[((c*NL + l)*NM + n)*2 + 0];
        float ph = disp[((c*NL + l)*NM + n)*2 + 1];
        dxc[c][l][n] = S2H * a * cosf(ph);
        dpc[c][l][n] = S2H * a * sinf(ph);
    } else if (t < 384) {
        int i = t - 192;
        int c = i / 96, rem = i % 96, l = rem / NM, n = rem % NM;
        float r  = fabsf(sq[((c*NL + l)*NM + n)*2 + 0]);
        float ph = sq[((c*NL + l)*NM + n)*2 + 1];
        float ch = coshf(r), sh = sinhf(r);
        float cp = cosf(ph), sp = sinf(ph);
        s00[c][l][n] = ch - cp*sh;
        s01[c][l][n] = -sp*sh;
        s11[c][l][n] = ch + cp*sh;
    } else if (t < 564) {
        int i = t - 384;
        int c = i / 90, rem = i % 90, l = rem / NW, w = rem % NW;
        float z  = bs[((c*NL + l)*NW + w)*2 + 0];
        float ph = bs[((c*NL + l)*NW + w)*2 + 1];
        float th = 1.0f / (1.0f + expf(-z));
        float ct = cosf(th), st = sinf(th);
        bct[c][l][w] = ct;
        bcs[c][l][w] = cosf(ph) * st;
        bss[c][l][w] = sinf(ph) * st;
    }
    __syncthreads();

    // Phase 2: 34 threads propagate basis vectors (pure FMA chain).
    // col < 16: linear column (no displacement). col == 16: bias (zero input
    // WITH displacement). Affine map F(x)=Mx+c decomposes exactly so.
    if (t >= 34) return;
    int c = t / 17;
    int col = t % 17;
    bool isBias = (col == NM);

    float mx[NM], mp[NM];
    #pragma unroll
    for (int n = 0; n < NM; ++n) { mx[n] = 0.f; mp[n] = 0.f; }
    if (!isBias) mx[col] = S2H;   // mx = S2H * x

    for (int l = 0; l < NL; ++l) {
        if (isBias) {
            #pragma unroll
            for (int n = 0; n < NM; ++n) { mx[n] += dxc[c][l][n]; mp[n] += dpc[c][l][n]; }
        }
        #pragma unroll
        for (int n = 0; n < NM; ++n) {
            float a = s00[c][l][n], b = s01[c][l][n], d = s11[c][l][n];
            float nx  = a*mx[n] + b*mp[n];
            float npp = b*mx[n] + d*mp[n];
            mx[n] = nx; mp[n] = npp;
        }
        #pragma unroll
        for (int w = 0; w < NW; ++w) {
            float ct = bct[c][l][w], cst = bcs[c][l][w], sst = bss[c][l][w];
            float x1 = mx[w], x2 = mx[w+1], p1 = mp[w], p2 = mp[w+1];
            mx[w]   = ct*x1  - cst*x2 - sst*p2;
            mx[w+1] = cst*x1 + ct*x2  - sst*p1;
            mp[w]   = sst*x2 + ct*p1  - cst*p2;
            mp[w+1] = sst*x1 + cst*p1 + ct*p2;
        }
    }

    if (c == 0) {
        if (!isBias) {
            #pragma unroll
            for (int n = 0; n < NM; ++n) ws[n*16 + col] = mx[n];
        } else {
            #pragma unroll
            for (int n = 0; n < NM; ++n) ws[512 + n] = mx[n];
        }
    } else {
        if (!isBias) {
            #pragma unroll
            for (int n = 0; n < NM; ++n) ws[(16 + n)*16 + col] = mp[n];
        } else {
            #pragma unroll
            for (int n = 0; n < NM; ++n) ws[512 + 16 + n] = mp[n];
        }
    }
}

__device__ __forceinline__ v4f dot4x16(const float xr[16],
                                       const float4 w[4][4],
                                       const float bias[4])
{
    float acc[4];
    #pragma unroll
    for (int j = 0; j < 4; ++j) acc[j] = bias[j];
    #pragma unroll
    for (int q = 0; q < 4; ++q) {
        #pragma unroll
        for (int j = 0; j < 4; ++j) {
            acc[j] = fmaf(w[j][q].x, xr[q*4+0], acc[j]);
            acc[j] = fmaf(w[j][q].y, xr[q*4+1], acc[j]);
            acc[j] = fmaf(w[j][q].z, xr[q*4+2], acc[j]);
            acc[j] = fmaf(w[j][q].w, xr[q*4+3], acc[j]);
        }
    }
    v4f r; r[0] = acc[0]; r[1] = acc[1]; r[2] = acc[2]; r[3] = acc[3];
    return r;
}

// Each thread produces float4 output chunks k = b*8 + c (out[b][4c..4c+4)).
// c = threadIdx.x & 7 is fixed per thread -> its 4 W rows + bias live in
// registers. Stores are lane-consecutive float4 -> 1 KB/wave contiguous, and
// NON-TEMPORAL (out is never re-read; skip L2 write-allocate). x loads stay
// cached: the 4x16B per-sample reads merge in L0/L1. Unroll x2 across the
// grid-stride for doubled loads-in-flight.
__global__ __launch_bounds__(256) void cv_apply(
    const float* __restrict__ x,
    const float* __restrict__ ws,
    float* __restrict__ out,
    long long nchunks)                  // B * 8
{
    const int c = threadIdx.x & 7;

    float4 w[4][4];
    float  bias[4];
    #pragma unroll
    for (int j = 0; j < 4; ++j) {
        const int n = c * 4 + j;
        #pragma unroll
        for (int q = 0; q < 4; ++q)
            w[j][q] = ((const float4*)ws)[n * 4 + q];
        bias[j] = ws[512 + n];
    }

    const long long G = (long long)gridDim.x * 256;
    v4f* __restrict__ outv = (v4f*)out;

    for (long long k = (long long)blockIdx.x * 256 + threadIdx.x;
         k < nchunks; k += 2 * G) {
        const long long k2 = k + G;
        const bool has2 = (k2 < nchunks);

        // Issue both x loads up front (independent, in flight together).
        float xr0[16], xr1[16];
        {
            const float4* xp = (const float4*)(x + (k >> 3) * 16);
            #pragma unroll
            for (int q = 0; q < 4; ++q) {
                float4 v = xp[q];
                xr0[q*4+0] = v.x; xr0[q*4+1] = v.y;
                xr0[q*4+2] = v.z; xr0[q*4+3] = v.w;
            }
        }
        if (has2) {
            const float4* xp = (const float4*)(x + (k2 >> 3) * 16);
            #pragma unroll
            for (int q = 0; q < 4; ++q) {
                float4 v = xp[q];
                xr1[q*4+0] = v.x; xr1[q*4+1] = v.y;
                xr1[q*4+2] = v.z; xr1[q*4+3] = v.w;
            }
        }

        __builtin_nontemporal_store(dot4x16(xr0, w, bias), outv + k);
        if (has2)
            __builtin_nontemporal_store(dot4x16(xr1, w, bias), outv + k2);
    }
}

extern "C" void kernel_launch(void* const* d_in, const int* in_sizes, int n_in,
                              void* d_out, int out_size, void* d_ws, size_t ws_size,
                              hipStream_t stream) {
    const float* x    = (const float*)d_in[0];
    const float* disp = (const float*)d_in[1];
    const float* sq   = (const float*)d_in[2];
    const float* bs   = (const float*)d_in[3];
    float* ws  = (float*)d_ws;
    float* out = (float*)d_out;

    long long B = in_sizes[0] / NM;
    long long nchunks = B * 8;

    cv_precompute<<<1, 640, 0, stream>>>(disp, sq, bs, ws);

    long long want = (nchunks + 255) / 256;
    int blocks = (int)(want < 2048 ? want : 2048);
    cv_apply<<<blocks, 256, 0, stream>>>(x, ws, out, nchunks);
}